// Round 1
// baseline (820.727 us; speedup 1.0000x reference)
//
#include <hip/hip_runtime.h>

#define SCALE_LORA 2.0f
#define BM 128
#define BN 128
#define BK 64

using bf16x8 = __attribute__((ext_vector_type(8))) __bf16;
using f32x4  = __attribute__((ext_vector_type(4))) float;
using u16x8  = __attribute__((ext_vector_type(8))) unsigned short;

static __device__ __forceinline__ unsigned short f2bf_rne(float f) {
  unsigned int u = __builtin_bit_cast(unsigned int, f);
  u += 0x7FFFu + ((u >> 16) & 1u);   // round-to-nearest-even
  return (unsigned short)(u >> 16);
}

// ---------- kernel 1: x f32 -> bf16 (vectorized, grid-stride) ----------
__global__ void cvt_bf16_kernel(const float* __restrict__ x,
                                unsigned short* __restrict__ xb, long n) {
  long stride = (long)gridDim.x * blockDim.x;
  long nv = n >> 3;
  for (long i = (long)blockIdx.x * blockDim.x + threadIdx.x; i < nv; i += stride) {
    long base = i << 3;
    f32x4 a = *(const f32x4*)(x + base);
    f32x4 b = *(const f32x4*)(x + base + 4);
    u16x8 o;
    o[0] = f2bf_rne(a[0]); o[1] = f2bf_rne(a[1]);
    o[2] = f2bf_rne(a[2]); o[3] = f2bf_rne(a[3]);
    o[4] = f2bf_rne(b[0]); o[5] = f2bf_rne(b[1]);
    o[6] = f2bf_rne(b[2]); o[7] = f2bf_rne(b[3]);
    *(u16x8*)(xb + base) = o;
  }
}

// ---------- kernel 2: W_eff^T = (W + 2*A@B)^T as bf16, N x K ----------
// 64(k) x 64(n) tile per block; coalesced read of W, LDS transpose,
// coalesced write of WT along k.
__global__ void build_wt_kernel(const float* __restrict__ W,
                                const float* __restrict__ A,
                                const float* __restrict__ Bmat,
                                unsigned short* __restrict__ WT,
                                int K, int N, int R) {
  __shared__ float Bs[16][64];
  __shared__ unsigned short Tt[64][66];   // +2 pad: conflict-free transpose read
  int ntn = N >> 6;
  int kt = blockIdx.x / ntn, nt = blockIdx.x - kt * ntn;
  int k0 = kt << 6, n0 = nt << 6;
  int t = threadIdx.x;
  int tx = t & 63, ty = t >> 6;   // tx: n (phase1) / k (phase2); ty: 0..3

  for (int i = t; i < R * 64; i += 256)
    Bs[i >> 6][i & 63] = Bmat[(long)(i >> 6) * N + n0 + (i & 63)];
  __syncthreads();

  for (int it = 0; it < 16; ++it) {
    int kl = (it << 2) + ty;
    long kg = k0 + kl;
    float w = W[kg * N + n0 + tx];
    const float* Ar = A + kg * R;
    float s = 0.f;
    for (int r = 0; r < R; ++r) s += Ar[r] * Bs[r][tx];
    Tt[kl][tx] = f2bf_rne(w + SCALE_LORA * s);
  }
  __syncthreads();

  for (int it = 0; it < 16; ++it) {
    int nn = (it << 2) + ty;
    WT[(long)(n0 + nn) * K + k0 + tx] = Tt[tx][nn];
  }
}

// ---------- kernel 3: out = Xb(bf16) @ WT(bf16)^T + bias, f32 out ----------
// 128x128 tile, BK=64, 4 waves (2x2), each wave 64x64 = 4x4 frags of 16x16x32.
__global__ __launch_bounds__(256, 2) void gemm_kernel(
    const unsigned short* __restrict__ Xb,  // M x K bf16
    const unsigned short* __restrict__ WT,  // N x K bf16 (pre-transposed)
    const float* __restrict__ bias,         // N f32
    float* __restrict__ out,                // M x N f32
    int M, int N, int K)
{
  __shared__ unsigned short As[BM * BK];    // [BM][BK] row-major, 16 KB
  __shared__ unsigned short Bs[BN * BK];    // [BN][BK] row-major, 16 KB

  // XCD-aware swizzle (bijective: nwg % 8 == 0 for this shape)
  int nwg = gridDim.x;
  int bid = blockIdx.x;
  if ((nwg & 7) == 0) {
    int cpx = nwg >> 3;
    bid = (bid & 7) * cpx + (bid >> 3);
  }
  int ntn = N / BN;
  int tm = bid / ntn;
  int tn = bid - tm * ntn;

  int t = threadIdx.x;
  int lane = t & 63;
  int wave = t >> 6;
  int wr = wave >> 1, wc = wave & 1;

  f32x4 acc[4][4] = {};

  const long m0 = (long)tm * BM;
  const long n0 = (long)tn * BN;
  const int flat0 = t * 16;   // byte offset within each 4 KB staging chunk

  for (int k0 = 0; k0 < K; k0 += BK) {
    // stage A(128x64) + B(128x64) bf16: 16 KB each, 4 chunks of 4 KB
    #pragma unroll
    for (int j = 0; j < 4; ++j) {
      int flat = j * 4096 + flat0;
      int row = flat >> 7;            // / (BK*2 bytes per row)
      int col = (flat & 127) >> 1;    // bf16 element within row
      __builtin_amdgcn_global_load_lds(
        (const __attribute__((address_space(1))) void*)(Xb + (m0 + row) * (long)K + k0 + col),
        (__attribute__((address_space(3))) void*)((char*)As + flat), 16, 0, 0);
      __builtin_amdgcn_global_load_lds(
        (const __attribute__((address_space(1))) void*)(WT + (n0 + row) * (long)K + k0 + col),
        (__attribute__((address_space(3))) void*)((char*)Bs + flat), 16, 0, 0);
    }
    __syncthreads();   // compiler emits vmcnt(0) drain + barrier

    #pragma unroll
    for (int ks = 0; ks < BK / 32; ++ks) {
      int kb = ks * 32 + ((lane >> 4) << 3);   // lane-group k base
      bf16x8 af[4], bfr[4];
      #pragma unroll
      for (int m = 0; m < 4; ++m) {
        int row = (wr << 6) + (m << 4) + (lane & 15);
        af[m] = *(const bf16x8*)(As + row * BK + kb);
      }
      #pragma unroll
      for (int n = 0; n < 4; ++n) {
        int rowb = (wc << 6) + (n << 4) + (lane & 15);
        bfr[n] = *(const bf16x8*)(Bs + rowb * BK + kb);
      }
      #pragma unroll
      for (int m = 0; m < 4; ++m)
        #pragma unroll
        for (int n = 0; n < 4; ++n)
          acc[m][n] = __builtin_amdgcn_mfma_f32_16x16x32_bf16(af[m], bfr[n], acc[m][n], 0, 0, 0);
    }
    __syncthreads();
  }

  // epilogue: C/D layout col = lane&15, row = (lane>>4)*4 + i  (m89-verified)
  #pragma unroll
  for (int n = 0; n < 4; ++n) {
    long col = n0 + (wc << 6) + (n << 4) + (lane & 15);
    float bv = bias[col];
    #pragma unroll
    for (int m = 0; m < 4; ++m) {
      long row0 = m0 + (wr << 6) + (m << 4) + ((lane >> 4) << 2);
      #pragma unroll
      for (int i = 0; i < 4; ++i)
        out[(row0 + i) * (long)N + col] = acc[m][n][i] + bv;
    }
  }
}

extern "C" void kernel_launch(void* const* d_in, const int* in_sizes, int n_in,
                              void* d_out, int out_size, void* d_ws, size_t ws_size,
                              hipStream_t stream) {
  const float* x    = (const float*)d_in[0];
  const float* W    = (const float*)d_in[1];
  const float* b    = (const float*)d_in[2];
  const float* A    = (const float*)d_in[3];
  const float* Bm   = (const float*)d_in[4];

  const long D_out = in_sizes[2];                 // 4096
  const long D_in  = (long)in_sizes[1] / D_out;   // 4096
  const long M     = (long)in_sizes[0] / D_in;    // 16384
  const int  R     = (int)((long)in_sizes[3] / D_in);  // 16
  const int  K = (int)D_in, N = (int)D_out;

  // workspace: [x as bf16 (M*K)] [W_eff^T as bf16 (N*K)] — needs 160 MiB
  unsigned short* xb = (unsigned short*)d_ws;
  unsigned short* wt = xb + (size_t)M * K;

  cvt_bf16_kernel<<<2048, 256, 0, stream>>>(x, xb, M * (long)K);
  build_wt_kernel<<<(K >> 6) * (N >> 6), 256, 0, stream>>>(W, A, Bm, wt, K, N, R);
  gemm_kernel<<<(int)((M / BM) * ((long)N / BN)), 256, 0, stream>>>(
      xb, wt, b, (float*)d_out, (int)M, N, K);
}

// Round 2
// 698.470 us; speedup vs baseline: 1.1750x; 1.1750x over previous
//
#include <hip/hip_runtime.h>

#define SCALE_LORA 2.0f
// GEMM geometry: 256x256 tile, BK=32, 8 waves (2M x 4N), 4-deep LDS ring
#define BM 256
#define BN 256
#define BK 32
#define NBUF 4
#define BUF_ELEMS 8192           // 256 rows x 32 cols bf16 per buffer slot

using bf16x8 = __attribute__((ext_vector_type(8))) __bf16;
using f32x4  = __attribute__((ext_vector_type(4))) float;
using u16x8  = __attribute__((ext_vector_type(8))) unsigned short;

static __device__ __forceinline__ unsigned short f2bf_rne(float f) {
  unsigned int u = __builtin_bit_cast(unsigned int, f);
  u += 0x7FFFu + ((u >> 16) & 1u);   // round-to-nearest-even
  return (unsigned short)(u >> 16);
}

// ---------- kernel 1: x f32 -> bf16 (vectorized, grid-stride) ----------
__global__ void cvt_bf16_kernel(const float* __restrict__ x,
                                unsigned short* __restrict__ xb, long n) {
  long stride = (long)gridDim.x * blockDim.x;
  long nv = n >> 3;
  for (long i = (long)blockIdx.x * blockDim.x + threadIdx.x; i < nv; i += stride) {
    long base = i << 3;
    f32x4 a = *(const f32x4*)(x + base);
    f32x4 b = *(const f32x4*)(x + base + 4);
    u16x8 o;
    o[0] = f2bf_rne(a[0]); o[1] = f2bf_rne(a[1]);
    o[2] = f2bf_rne(a[2]); o[3] = f2bf_rne(a[3]);
    o[4] = f2bf_rne(b[0]); o[5] = f2bf_rne(b[1]);
    o[6] = f2bf_rne(b[2]); o[7] = f2bf_rne(b[3]);
    *(u16x8*)(xb + base) = o;
  }
}

// ---------- kernel 2: W_eff^T = (W + 2*A@B)^T as bf16, N x K ----------
__global__ void build_wt_kernel(const float* __restrict__ W,
                                const float* __restrict__ A,
                                const float* __restrict__ Bmat,
                                unsigned short* __restrict__ WT,
                                int K, int N, int R) {
  __shared__ float Bs[16][64];
  __shared__ unsigned short Tt[64][66];   // +2 pad: conflict-free transpose read
  int ntn = N >> 6;
  int kt = blockIdx.x / ntn, nt = blockIdx.x - kt * ntn;
  int k0 = kt << 6, n0 = nt << 6;
  int t = threadIdx.x;
  int tx = t & 63, ty = t >> 6;

  for (int i = t; i < R * 64; i += 256)
    Bs[i >> 6][i & 63] = Bmat[(long)(i >> 6) * N + n0 + (i & 63)];
  __syncthreads();

  for (int it = 0; it < 16; ++it) {
    int kl = (it << 2) + ty;
    long kg = k0 + kl;
    float w = W[kg * N + n0 + tx];
    const float* Ar = A + kg * R;
    float s = 0.f;
    for (int r = 0; r < R; ++r) s += Ar[r] * Bs[r][tx];
    Tt[kl][tx] = f2bf_rne(w + SCALE_LORA * s);
  }
  __syncthreads();

  for (int it = 0; it < 16; ++it) {
    int nn = (it << 2) + ty;
    WT[(long)(n0 + nn) * K + k0 + tx] = Tt[tx][nn];
  }
}

// ---------- kernel 3: deep-pipelined 256x256 GEMM, counted vmcnt ----------
// LDS swizzle (rows are 64 B): byte ^= ((row>>1)&3)<<4. Applied as
// inverse-swizzled GLOBAL SOURCE (linear global_load_lds dest) + swizzled
// ds_read address (XOR involution, both-sides rule).
__global__ __launch_bounds__(512, 2) void gemm_kernel(
    const unsigned short* __restrict__ Xb,  // M x K bf16
    const unsigned short* __restrict__ WT,  // N x K bf16 (pre-transposed)
    const float* __restrict__ bias,         // N f32
    float* __restrict__ out,                // M x N f32
    int M, int N, int K)
{
  extern __shared__ unsigned short lds[];          // 128 KiB dynamic
  unsigned short* Asl = lds;                       // 4 bufs x 8192 elems
  unsigned short* Bsl = lds + NBUF * BUF_ELEMS;    // 4 bufs x 8192 elems

  // XCD-aware bijective swizzle (nwg = 1024, % 8 == 0)
  int nwg = gridDim.x;
  int bid = blockIdx.x;
  if ((nwg & 7) == 0) {
    int cpx = nwg >> 3;
    bid = (bid & 7) * cpx + (bid >> 3);
  }
  int ntn = N / BN;
  int tm = bid / ntn;
  int tn = bid - tm * ntn;
  const long m0 = (long)tm * BM;
  const long n0 = (long)tn * BN;

  int tid  = threadIdx.x;
  int lane = tid & 63;
  int wave = tid >> 6;
  int wr = wave >> 2;        // 0..1 : 128-row half
  int wc = wave & 3;         // 0..3 : 64-col quarter
  int l15 = lane & 15;
  int g   = lane >> 4;       // 16B granule / k-subgroup

  f32x4 acc[8][4] = {};

  // ---- staging addresses (per-thread, j-independent source swizzle) ----
  // flat byte fb = j*8192 + tid*16 ; row = j*128 + (tid>>2)
  // source col (elems) = 8 * ((tid&3) ^ ((tid>>3)&3))
  int srccol = 8 * ((tid & 3) ^ ((tid >> 3) & 3));
  const unsigned short* aSrc = Xb + (m0 + (tid >> 2)) * (long)K + srccol;
  const unsigned short* bSrc = WT + (n0 + (tid >> 2)) * (long)K + srccol;
  const int ldsFlat = tid * 16;   // byte offset within 8 KB half-chunk

  // ---- fragment read offsets (swizzled) ----
  int swzg = g ^ ((l15 >> 1) & 3);
  int fragA = (wr * 128 + l15) * BK + 8 * swzg;   // elems; m adds 512
  int fragB = (wc * 64  + l15) * BK + 8 * swzg;   // elems; n adds 512

  const int nt = K / BK;   // 128 K-tiles

#define STAGE(buf, kt) do {                                                  \
    long koff_ = (long)(kt) * BK;                                            \
    _Pragma("unroll")                                                        \
    for (int j_ = 0; j_ < 2; ++j_) {                                         \
      __builtin_amdgcn_global_load_lds(                                      \
        (const __attribute__((address_space(1))) void*)(aSrc + j_*128*(long)K + koff_), \
        (__attribute__((address_space(3))) void*)((char*)Asl + (buf)*16384 + j_*8192 + ldsFlat), \
        16, 0, 0);                                                           \
      __builtin_amdgcn_global_load_lds(                                      \
        (const __attribute__((address_space(1))) void*)(bSrc + j_*128*(long)K + koff_), \
        (__attribute__((address_space(3))) void*)((char*)Bsl + (buf)*16384 + j_*8192 + ldsFlat), \
        16, 0, 0);                                                           \
    }                                                                        \
  } while (0)

#define COMPUTE(buf) do {                                                    \
    const unsigned short* ab_ = Asl + (buf) * BUF_ELEMS + fragA;             \
    const unsigned short* bb_ = Bsl + (buf) * BUF_ELEMS + fragB;             \
    bf16x8 af_[8], bf_[4];                                                   \
    _Pragma("unroll")                                                        \
    for (int m_ = 0; m_ < 8; ++m_) af_[m_] = *(const bf16x8*)(ab_ + m_*512); \
    _Pragma("unroll")                                                        \
    for (int n_ = 0; n_ < 4; ++n_) bf_[n_] = *(const bf16x8*)(bb_ + n_*512); \
    __builtin_amdgcn_s_setprio(1);                                           \
    _Pragma("unroll")                                                        \
    for (int m_ = 0; m_ < 8; ++m_)                                           \
      _Pragma("unroll")                                                      \
      for (int n_ = 0; n_ < 4; ++n_)                                         \
        acc[m_][n_] = __builtin_amdgcn_mfma_f32_16x16x32_bf16(               \
            af_[m_], bf_[n_], acc[m_][n_], 0, 0, 0);                         \
    __builtin_amdgcn_s_setprio(0);                                           \
  } while (0)

  // ---- prologue: 3-deep prefetch (12 loads in flight) ----
  STAGE(0, 0);
  STAGE(1, 1);
  STAGE(2, 2);

  // ---- steady state: issue tile t+3, wait tile t (vmcnt 16->12) ----
  for (int t = 0; t < nt - 3; ++t) {
    STAGE((t + 3) & 3, t + 3);
    asm volatile("s_waitcnt vmcnt(12)" ::: "memory");
    __builtin_amdgcn_s_barrier();
    __builtin_amdgcn_sched_barrier(0);
    COMPUTE(t & 3);
    __builtin_amdgcn_s_barrier();
  }

  // ---- epilogue drain: 12 -> 8 -> 4 -> 0 ----
  asm volatile("s_waitcnt vmcnt(8)" ::: "memory");
  __builtin_amdgcn_s_barrier();
  __builtin_amdgcn_sched_barrier(0);
  COMPUTE((nt - 3) & 3);
  __builtin_amdgcn_s_barrier();

  asm volatile("s_waitcnt vmcnt(4)" ::: "memory");
  __builtin_amdgcn_s_barrier();
  __builtin_amdgcn_sched_barrier(0);
  COMPUTE((nt - 2) & 3);
  __builtin_amdgcn_s_barrier();

  asm volatile("s_waitcnt vmcnt(0)" ::: "memory");
  __builtin_amdgcn_s_barrier();
  __builtin_amdgcn_sched_barrier(0);
  COMPUTE((nt - 1) & 3);

#undef STAGE
#undef COMPUTE

  // ---- epilogue: C/D layout col = lane&15, row = (lane>>4)*4 + i ----
  #pragma unroll
  for (int n = 0; n < 4; ++n) {
    long col = n0 + wc * 64 + n * 16 + l15;
    float bv = bias[col];
    #pragma unroll
    for (int m = 0; m < 8; ++m) {
      long row0 = m0 + wr * 128 + m * 16 + (g << 2);
      #pragma unroll
      for (int i = 0; i < 4; ++i)
        out[(row0 + i) * (long)N + col] = acc[m][n][i] + bv;
    }
  }
}

extern "C" void kernel_launch(void* const* d_in, const int* in_sizes, int n_in,
                              void* d_out, int out_size, void* d_ws, size_t ws_size,
                              hipStream_t stream) {
  const float* x    = (const float*)d_in[0];
  const float* W    = (const float*)d_in[1];
  const float* b    = (const float*)d_in[2];
  const float* A    = (const float*)d_in[3];
  const float* Bm   = (const float*)d_in[4];

  const long D_out = in_sizes[2];                 // 4096
  const long D_in  = (long)in_sizes[1] / D_out;   // 4096
  const long M     = (long)in_sizes[0] / D_in;    // 16384
  const int  R     = (int)((long)in_sizes[3] / D_in);  // 16
  const int  K = (int)D_in, N = (int)D_out;

  unsigned short* xb = (unsigned short*)d_ws;
  unsigned short* wt = xb + (size_t)M * K;

  cvt_bf16_kernel<<<2048, 256, 0, stream>>>(x, xb, M * (long)K);
  build_wt_kernel<<<(K >> 6) * (N >> 6), 256, 0, stream>>>(W, A, Bm, wt, K, N, R);

  int grid = (int)((M / BM) * ((long)N / BN));    // 64 * 16 = 1024
  gemm_kernel<<<grid, 512, 128 * 1024, stream>>>(
      xb, wt, b, (float*)d_out, (int)M, N, K);
}

// Round 3
// 646.698 us; speedup vs baseline: 1.2691x; 1.0801x over previous
//
#include <hip/hip_runtime.h>

#define SCALE_LORA 2.0f
// GEMM: 256x256 tile, BK=32, 8 waves (2M x 4N), 4-deep LDS ring, 2-phase/K-tile
#define BM 256
#define BN 256
#define BK 32
#define NBUF 4
#define BUF_ELEMS 8192           // 256 rows x 32 cols bf16 per buffer slot

using bf16x8 = __attribute__((ext_vector_type(8))) __bf16;
using f32x4  = __attribute__((ext_vector_type(4))) float;
using u16x8  = __attribute__((ext_vector_type(8))) unsigned short;

static __device__ __forceinline__ unsigned short f2bf_rne(float f) {
  unsigned int u = __builtin_bit_cast(unsigned int, f);
  u += 0x7FFFu + ((u >> 16) & 1u);   // round-to-nearest-even
  return (unsigned short)(u >> 16);
}

// ---------- kernel 1: x f32 -> bf16 (vectorized, grid-stride) ----------
__global__ void cvt_bf16_kernel(const float* __restrict__ x,
                                unsigned short* __restrict__ xb, long n) {
  long stride = (long)gridDim.x * blockDim.x;
  long nv = n >> 3;
  for (long i = (long)blockIdx.x * blockDim.x + threadIdx.x; i < nv; i += stride) {
    long base = i << 3;
    f32x4 a = *(const f32x4*)(x + base);
    f32x4 b = *(const f32x4*)(x + base + 4);
    u16x8 o;
    o[0] = f2bf_rne(a[0]); o[1] = f2bf_rne(a[1]);
    o[2] = f2bf_rne(a[2]); o[3] = f2bf_rne(a[3]);
    o[4] = f2bf_rne(b[0]); o[5] = f2bf_rne(b[1]);
    o[6] = f2bf_rne(b[2]); o[7] = f2bf_rne(b[3]);
    *(u16x8*)(xb + base) = o;
  }
}

// ---------- kernel 2: W_eff^T = (W + 2*A@B)^T as bf16, N x K ----------
__global__ void build_wt_kernel(const float* __restrict__ W,
                                const float* __restrict__ A,
                                const float* __restrict__ Bmat,
                                unsigned short* __restrict__ WT,
                                int K, int N, int R) {
  __shared__ float Bs[16][64];
  __shared__ unsigned short Tt[64][66];
  int ntn = N >> 6;
  int kt = blockIdx.x / ntn, nt = blockIdx.x - kt * ntn;
  int k0 = kt << 6, n0 = nt << 6;
  int t = threadIdx.x;
  int tx = t & 63, ty = t >> 6;

  for (int i = t; i < R * 64; i += 256)
    Bs[i >> 6][i & 63] = Bmat[(long)(i >> 6) * N + n0 + (i & 63)];
  __syncthreads();

  for (int it = 0; it < 16; ++it) {
    int kl = (it << 2) + ty;
    long kg = k0 + kl;
    float w = W[kg * N + n0 + tx];
    const float* Ar = A + kg * R;
    float s = 0.f;
    for (int r = 0; r < R; ++r) s += Ar[r] * Bs[r][tx];
    Tt[kl][tx] = f2bf_rne(w + SCALE_LORA * s);
  }
  __syncthreads();

  for (int it = 0; it < 16; ++it) {
    int nn = (it << 2) + ty;
    WT[(long)(n0 + nn) * K + k0 + tx] = Tt[tx][nn];
  }
}

// ---------- kernel 3: 2-phase-per-K-tile deep-pipelined GEMM ----------
__global__ __launch_bounds__(512, 2) void gemm_kernel(
    const unsigned short* __restrict__ Xb,  // M x K bf16
    const unsigned short* __restrict__ WT,  // N x K bf16 (pre-transposed)
    const float* __restrict__ bias,         // N f32
    float* __restrict__ out,                // M x N f32
    int M, int N, int K)
{
  extern __shared__ unsigned short lds[];          // 128 KiB dynamic
  unsigned short* Asl = lds;                       // 4 bufs x 8192 elems
  unsigned short* Bsl = lds + NBUF * BUF_ELEMS;

  // XCD-aware bijective swizzle (nwg = 1024, % 8 == 0)
  int nwg = gridDim.x;
  int bid = blockIdx.x;
  if ((nwg & 7) == 0) {
    int cpx = nwg >> 3;
    bid = (bid & 7) * cpx + (bid >> 3);
  }
  int ntn = N / BN;
  int tm = bid / ntn;
  int tn = bid - tm * ntn;
  const long m0 = (long)tm * BM;
  const long n0 = (long)tn * BN;

  int tid  = threadIdx.x;
  int lane = tid & 63;
  int wave = tid >> 6;
  int wr = wave >> 2;        // 0..1 : 128-row half
  int wc = wave & 3;         // 0..3 : 64-col quarter
  int l15 = lane & 15;
  int g   = lane >> 4;

  f32x4 acc[8][4] = {};

  // staging: linear LDS dest + inverse-swizzled global source col
  int srccol = 8 * ((tid & 3) ^ ((tid >> 3) & 3));
  const unsigned short* aSrc = Xb + (m0 + (tid >> 2)) * (long)K + srccol;
  const unsigned short* bSrc = WT + (n0 + (tid >> 2)) * (long)K + srccol;
  const int ldsFlat = tid * 16;

  // fragment read offsets (swizzled: byte ^= ((row>>1)&3)<<4)
  int swzg = g ^ ((l15 >> 1) & 3);
  int fragA = (wr * 128 + l15) * BK + 8 * swzg;   // + m*512
  int fragB = (wc * 64  + l15) * BK + 8 * swzg;   // + n*512

  const int nt = K / BK;   // 128

#define STAGEA(buf, kt) do { long koff_ = (long)(kt) * BK;                   \
    _Pragma("unroll")                                                        \
    for (int j_ = 0; j_ < 2; ++j_)                                           \
      __builtin_amdgcn_global_load_lds(                                      \
        (const __attribute__((address_space(1))) void*)(aSrc + j_*128*(long)K + koff_), \
        (__attribute__((address_space(3))) void*)((char*)Asl + (buf)*16384 + j_*8192 + ldsFlat), \
        16, 0, 0);                                                           \
  } while (0)

#define STAGEB(buf, kt) do { long koff_ = (long)(kt) * BK;                   \
    _Pragma("unroll")                                                        \
    for (int j_ = 0; j_ < 2; ++j_)                                           \
      __builtin_amdgcn_global_load_lds(                                      \
        (const __attribute__((address_space(1))) void*)(bSrc + j_*128*(long)K + koff_), \
        (__attribute__((address_space(3))) void*)((char*)Bsl + (buf)*16384 + j_*8192 + ldsFlat), \
        16, 0, 0);                                                           \
  } while (0)

  // One K-tile: vmcnt + barrier, then 2 phases of
  // {ds_read subtile ∥ stage-half → SB(0) → barrier → setprio/16 MFMA → barrier}
#define TILE(BUFI, VMSTR, SA, SB) do {                                       \
    asm volatile("s_waitcnt vmcnt(" VMSTR ")" ::: "memory");                 \
    __builtin_amdgcn_s_barrier();                                            \
    const unsigned short* ab_ = Asl + (BUFI) * BUF_ELEMS + fragA;            \
    const unsigned short* bb_ = Bsl + (BUFI) * BUF_ELEMS + fragB;            \
    bf16x8 af_[4], bf_[4];                                                   \
    _Pragma("unroll")                                                        \
    for (int m_ = 0; m_ < 4; ++m_) af_[m_] = *(const bf16x8*)(ab_ + m_*512); \
    _Pragma("unroll")                                                        \
    for (int n_ = 0; n_ < 4; ++n_) bf_[n_] = *(const bf16x8*)(bb_ + n_*512); \
    SA;                                                                      \
    __builtin_amdgcn_sched_barrier(0);                                       \
    __builtin_amdgcn_s_barrier();                                            \
    __builtin_amdgcn_s_setprio(1);                                           \
    _Pragma("unroll")                                                        \
    for (int m_ = 0; m_ < 4; ++m_)                                           \
      _Pragma("unroll")                                                      \
      for (int n_ = 0; n_ < 4; ++n_)                                         \
        acc[m_][n_] = __builtin_amdgcn_mfma_f32_16x16x32_bf16(               \
            af_[m_], bf_[n_], acc[m_][n_], 0, 0, 0);                         \
    __builtin_amdgcn_s_setprio(0);                                           \
    __builtin_amdgcn_sched_barrier(0);                                       \
    __builtin_amdgcn_s_barrier();                                            \
    bf16x8 ag_[4];                                                           \
    _Pragma("unroll")                                                        \
    for (int m_ = 0; m_ < 4; ++m_) ag_[m_] = *(const bf16x8*)(ab_ + (m_+4)*512); \
    SB;                                                                      \
    __builtin_amdgcn_sched_barrier(0);                                       \
    __builtin_amdgcn_s_barrier();                                            \
    __builtin_amdgcn_s_setprio(1);                                           \
    _Pragma("unroll")                                                        \
    for (int m_ = 0; m_ < 4; ++m_)                                           \
      _Pragma("unroll")                                                      \
      for (int n_ = 0; n_ < 4; ++n_)                                         \
        acc[m_+4][n_] = __builtin_amdgcn_mfma_f32_16x16x32_bf16(             \
            ag_[m_], bf_[n_], acc[m_+4][n_], 0, 0, 0);                       \
    __builtin_amdgcn_s_setprio(0);                                           \
    __builtin_amdgcn_sched_barrier(0);                                       \
  } while (0)

  // prologue: 3 K-tiles in flight (12 loads)
  STAGEA(0, 0); STAGEB(0, 0);
  STAGEA(1, 1); STAGEB(1, 1);
  STAGEA(2, 2); STAGEB(2, 2);

  // steady state: at tile top 12 in flight; vmcnt(8) lands tile t
  for (int t = 0; t < nt - 3; ++t) {
    int slot = (t + 3) & 3;
    TILE(t & 3, "8", STAGEA(slot, t + 3), STAGEB(slot, t + 3));
  }
  // drain: 12 -> 8 -> 4 -> 0 outstanding
  TILE((nt - 3) & 3, "8", , );
  TILE((nt - 2) & 3, "4", , );
  TILE((nt - 1) & 3, "0", , );

#undef TILE
#undef STAGEA
#undef STAGEB

  // epilogue: C/D layout col = lane&15, row = (lane>>4)*4 + i
  #pragma unroll
  for (int n = 0; n < 4; ++n) {
    long col = n0 + wc * 64 + n * 16 + l15;
    float bv = bias[col];
    #pragma unroll
    for (int m = 0; m < 8; ++m) {
      long row0 = m0 + wr * 128 + m * 16 + (g << 2);
      #pragma unroll
      for (int i = 0; i < 4; ++i)
        out[(row0 + i) * (long)N + col] = acc[m][n][i] + bv;
    }
  }
}

extern "C" void kernel_launch(void* const* d_in, const int* in_sizes, int n_in,
                              void* d_out, int out_size, void* d_ws, size_t ws_size,
                              hipStream_t stream) {
  const float* x    = (const float*)d_in[0];
  const float* W    = (const float*)d_in[1];
  const float* b    = (const float*)d_in[2];
  const float* A    = (const float*)d_in[3];
  const float* Bm   = (const float*)d_in[4];

  const long D_out = in_sizes[2];                 // 4096
  const long D_in  = (long)in_sizes[1] / D_out;   // 4096
  const long M     = (long)in_sizes[0] / D_in;    // 16384
  const int  R     = (int)((long)in_sizes[3] / D_in);  // 16
  const int  K = (int)D_in, N = (int)D_out;

  unsigned short* xb = (unsigned short*)d_ws;
  unsigned short* wt = xb + (size_t)M * K;

  cvt_bf16_kernel<<<2048, 256, 0, stream>>>(x, xb, M * (long)K);
  build_wt_kernel<<<(K >> 6) * (N >> 6), 256, 0, stream>>>(W, A, Bm, wt, K, N, R);

  int grid = (int)((M / BM) * ((long)N / BN));    // 64 * 16 = 1024
  gemm_kernel<<<grid, 512, 128 * 1024, stream>>>(
      xb, wt, b, (float*)d_out, (int)M, N, K);
}

// Round 4
// 623.593 us; speedup vs baseline: 1.3161x; 1.0371x over previous
//
#include <hip/hip_runtime.h>

#define SCALE_LORA 2.0f
// GEMM: 256x256 tile, BK=64, 8 waves (2M x 4N), NBUF=2, 4 quadrant-phases/tile
#define BM 256
#define BN 256
#define BK 64

#define AS1 __attribute__((address_space(1)))
#define AS3 __attribute__((address_space(3)))

using bf16x8 = __attribute__((ext_vector_type(8))) __bf16;
using f32x4  = __attribute__((ext_vector_type(4))) float;
using u16x8  = __attribute__((ext_vector_type(8))) unsigned short;

#define MFMA(a, b, c) __builtin_amdgcn_mfma_f32_16x16x32_bf16((a), (b), (c), 0, 0, 0)

static __device__ __forceinline__ unsigned short f2bf_rne(float f) {
  unsigned int u = __builtin_bit_cast(unsigned int, f);
  u += 0x7FFFu + ((u >> 16) & 1u);   // round-to-nearest-even
  return (unsigned short)(u >> 16);
}

// ---------- kernel 1: x f32 -> bf16 (vectorized, grid-stride) ----------
__global__ void cvt_bf16_kernel(const float* __restrict__ x,
                                unsigned short* __restrict__ xb, long n) {
  long stride = (long)gridDim.x * blockDim.x;
  long nv = n >> 3;
  for (long i = (long)blockIdx.x * blockDim.x + threadIdx.x; i < nv; i += stride) {
    long base = i << 3;
    f32x4 a = *(const f32x4*)(x + base);
    f32x4 b = *(const f32x4*)(x + base + 4);
    u16x8 o;
    o[0] = f2bf_rne(a[0]); o[1] = f2bf_rne(a[1]);
    o[2] = f2bf_rne(a[2]); o[3] = f2bf_rne(a[3]);
    o[4] = f2bf_rne(b[0]); o[5] = f2bf_rne(b[1]);
    o[6] = f2bf_rne(b[2]); o[7] = f2bf_rne(b[3]);
    *(u16x8*)(xb + base) = o;
  }
}

// ---------- kernel 2: W_eff^T = (W + 2*A@B)^T as bf16, N x K ----------
__global__ void build_wt_kernel(const float* __restrict__ W,
                                const float* __restrict__ A,
                                const float* __restrict__ Bmat,
                                unsigned short* __restrict__ WT,
                                int K, int N, int R) {
  __shared__ float Bs[16][64];
  __shared__ unsigned short Tt[64][66];
  int ntn = N >> 6;
  int kt = blockIdx.x / ntn, nt = blockIdx.x - kt * ntn;
  int k0 = kt << 6, n0 = nt << 6;
  int t = threadIdx.x;
  int tx = t & 63, ty = t >> 6;

  for (int i = t; i < R * 64; i += 256)
    Bs[i >> 6][i & 63] = Bmat[(long)(i >> 6) * N + n0 + (i & 63)];
  __syncthreads();

  for (int it = 0; it < 16; ++it) {
    int kl = (it << 2) + ty;
    long kg = k0 + kl;
    float w = W[kg * N + n0 + tx];
    const float* Ar = A + kg * R;
    float s = 0.f;
    for (int r = 0; r < R; ++r) s += Ar[r] * Bs[r][tx];
    Tt[kl][tx] = f2bf_rne(w + SCALE_LORA * s);
  }
  __syncthreads();

  for (int it = 0; it < 16; ++it) {
    int nn = (it << 2) + ty;
    WT[(long)(n0 + nn) * K + k0 + tx] = Tt[tx][nn];
  }
}

// ---------- kernel 3: BK=64, 4 quadrant-phases/tile, distributed staging ----
// Rows are 128 B -> swizzle byte ^= (row&7)<<4, applied as inverse-swizzled
// GLOBAL SOURCE (linear gload_lds dest) + swizzled ds_read addr (involution).
__global__ __launch_bounds__(512, 2) void gemm_kernel(
    const unsigned short* __restrict__ Xb,  // M x K bf16
    const unsigned short* __restrict__ WT,  // N x K bf16 (pre-transposed)
    const float* __restrict__ bias,         // N f32
    float* __restrict__ out,                // M x N f32
    int M, int N, int K)
{
  extern __shared__ unsigned short lds[];   // 128 KiB
  // A bufs: elems [0,16384),[16384,32768); B bufs: [32768,49152),[49152,65536)

  int nwg = gridDim.x;
  int bid = blockIdx.x;
  if ((nwg & 7) == 0) {
    int cpx = nwg >> 3;
    bid = (bid & 7) * cpx + (bid >> 3);
  }
  int ntn = N / BN;
  int tm = bid / ntn;
  int tn = bid - tm * ntn;
  const long m0 = (long)tm * BM;
  const long n0 = (long)tn * BN;

  int tid  = threadIdx.x;
  int lane = tid & 63;
  int wave = tid >> 6;
  int wr = wave >> 2;        // 0..1 : 128-row half (M)
  int wc = wave & 3;         // 0..3 : 64-col quarter (N)
  int l15 = lane & 15;
  int g   = lane >> 4;

  f32x4 acc[8][4] = {};

  // staging: thread t covers row = t>>3, source-col granule = (t&7)^(row&7)
  int srccol = 8 * ((tid & 7) ^ ((tid >> 3) & 7));
  const unsigned short* aSrc = Xb + (m0 + (tid >> 3)) * (long)K + srccol;
  const unsigned short* bSrc = WT + (n0 + (tid >> 3)) * (long)K + srccol;
  const int ldsByte = tid * 16;

  // fragment read bases (elems), swizzled: granule = ((kh<<2)|g) ^ (row&7)
  const int fragA = (wr * 128 + l15) * 64 + 8 * (g ^ (l15 & 3));
  const int fragB = (wc * 64  + l15) * 64 + 8 * (g ^ (l15 & 3));
  const int kx0 = ((l15 >> 2) & 1) << 5;   // 0 or 32 elems
  const int kx1 = kx0 ^ 32;

  const int nt = K / BK;   // 64

#define STAGEA(buf, kt) do { long ko_ = (long)(kt) * BK;                     \
    _Pragma("unroll")                                                        \
    for (int j_ = 0; j_ < 4; ++j_)                                           \
      __builtin_amdgcn_global_load_lds(                                      \
        (const AS1 void*)(aSrc + j_*64*(long)K + ko_),                       \
        (AS3 void*)((char*)lds + (buf)*32768 + j_*8192 + ldsByte), 16,0,0);  \
  } while (0)

#define STAGEB(buf, kt) do { long ko_ = (long)(kt) * BK;                     \
    _Pragma("unroll")                                                        \
    for (int j_ = 0; j_ < 4; ++j_)                                           \
      __builtin_amdgcn_global_load_lds(                                      \
        (const AS1 void*)(bSrc + j_*64*(long)K + ko_),                       \
        (AS3 void*)((char*)lds + 65536 + (buf)*32768 + j_*8192 + ldsByte),   \
        16,0,0);                                                             \
  } while (0)

#define SBAR  __builtin_amdgcn_sched_barrier(0)
#define BAR   __builtin_amdgcn_s_barrier()

#define TILE(BUFI, VMSTR, SBST, SAST) do {                                   \
    asm volatile("s_waitcnt vmcnt(" VMSTR ")" ::: "memory");                 \
    BAR;                                                                     \
    const unsigned short* Ab_ = lds + (BUFI)*16384 + fragA;                  \
    const unsigned short* Bb_ = lds + 32768 + (BUFI)*16384 + fragB;          \
    bf16x8 af_[4][2], bl_[2][2], bh_[2][2], ag_[4][2];                       \
    /* ---- phase 1: A-lo + B-lo reads, MFMA quad (m0-3, n0-1) ---- */       \
    _Pragma("unroll")                                                        \
    for (int m_ = 0; m_ < 4; ++m_) {                                         \
      af_[m_][0] = *(const bf16x8*)(Ab_ + m_*1024 + kx0);                    \
      af_[m_][1] = *(const bf16x8*)(Ab_ + m_*1024 + kx1); }                  \
    _Pragma("unroll")                                                        \
    for (int n_ = 0; n_ < 2; ++n_) {                                         \
      bl_[n_][0] = *(const bf16x8*)(Bb_ + n_*1024 + kx0);                    \
      bl_[n_][1] = *(const bf16x8*)(Bb_ + n_*1024 + kx1); }                  \
    SBAR; BAR;                                                               \
    __builtin_amdgcn_s_setprio(1);                                           \
    _Pragma("unroll")                                                        \
    for (int m_ = 0; m_ < 4; ++m_)                                           \
      _Pragma("unroll")                                                      \
      for (int n_ = 0; n_ < 2; ++n_) {                                       \
        acc[m_][n_] = MFMA(af_[m_][0], bl_[n_][0], acc[m_][n_]);             \
        acc[m_][n_] = MFMA(af_[m_][1], bl_[n_][1], acc[m_][n_]); }           \
    __builtin_amdgcn_s_setprio(0);                                           \
    SBAR; BAR;                                                               \
    /* ---- phase 2: B-hi reads, MFMA quad (m0-3, n2-3) ---- */              \
    _Pragma("unroll")                                                        \
    for (int n_ = 0; n_ < 2; ++n_) {                                         \
      bh_[n_][0] = *(const bf16x8*)(Bb_ + (n_+2)*1024 + kx0);                \
      bh_[n_][1] = *(const bf16x8*)(Bb_ + (n_+2)*1024 + kx1); }              \
    SBAR; BAR;                                                               \
    __builtin_amdgcn_s_setprio(1);                                           \
    _Pragma("unroll")                                                        \
    for (int m_ = 0; m_ < 4; ++m_)                                           \
      _Pragma("unroll")                                                      \
      for (int n_ = 0; n_ < 2; ++n_) {                                       \
        acc[m_][n_+2] = MFMA(af_[m_][0], bh_[n_][0], acc[m_][n_+2]);         \
        acc[m_][n_+2] = MFMA(af_[m_][1], bh_[n_][1], acc[m_][n_+2]); }       \
    __builtin_amdgcn_s_setprio(0);                                           \
    SBAR; BAR;                                                               \
    /* ---- phase 3: A-hi reads, stage B(t+2); MFMA quad (m4-7, n0-1) ---- */\
    _Pragma("unroll")                                                        \
    for (int m_ = 0; m_ < 4; ++m_) {                                         \
      ag_[m_][0] = *(const bf16x8*)(Ab_ + (m_+4)*1024 + kx0);                \
      ag_[m_][1] = *(const bf16x8*)(Ab_ + (m_+4)*1024 + kx1); }              \
    SBST;                                                                    \
    SBAR; BAR;                                                               \
    __builtin_amdgcn_s_setprio(1);                                           \
    _Pragma("unroll")                                                        \
    for (int m_ = 0; m_ < 4; ++m_)                                           \
      _Pragma("unroll")                                                      \
      for (int n_ = 0; n_ < 2; ++n_) {                                       \
        acc[m_+4][n_] = MFMA(ag_[m_][0], bl_[n_][0], acc[m_+4][n_]);         \
        acc[m_+4][n_] = MFMA(ag_[m_][1], bl_[n_][1], acc[m_+4][n_]); }       \
    __builtin_amdgcn_s_setprio(0);                                           \
    SBAR; BAR;                                                               \
    /* ---- phase 4: stage A(t+2); MFMA quad (m4-7, n2-3) ---- */            \
    SAST;                                                                    \
    SBAR;                                                                    \
    __builtin_amdgcn_s_setprio(1);                                           \
    _Pragma("unroll")                                                        \
    for (int m_ = 0; m_ < 4; ++m_)                                           \
      _Pragma("unroll")                                                      \
      for (int n_ = 0; n_ < 2; ++n_) {                                       \
        acc[m_+4][n_+2] = MFMA(ag_[m_][0], bh_[n_][0], acc[m_+4][n_+2]);     \
        acc[m_+4][n_+2] = MFMA(ag_[m_][1], bh_[n_][1], acc[m_+4][n_+2]); }   \
    __builtin_amdgcn_s_setprio(0);                                           \
    SBAR;                                                                    \
  } while (0)

  // prologue: tiles 0,1 staged (16 loads in flight)
  STAGEA(0, 0); STAGEB(0, 0);
  STAGEA(1, 1); STAGEB(1, 1);

  // steady state: read buf t&1; stage tile t+2 into the same buf index,
  // issued only after the barriers that close all reads of that region.
  for (int t = 0; t < nt - 2; ++t) {
    TILE(t & 1, "8", STAGEB(t & 1, t + 2), STAGEA(t & 1, t + 2));
  }
  TILE(nt & 1, "8", , );        // tile nt-2  ((nt-2)&1 == nt&1)
  TILE(1 - (nt & 1), "0", , );  // tile nt-1

#undef TILE
#undef STAGEA
#undef STAGEB

  // epilogue: C/D layout col = lane&15, row = (lane>>4)*4 + i
  #pragma unroll
  for (int n = 0; n < 4; ++n) {
    long col = n0 + wc * 64 + n * 16 + l15;
    float bv = bias[col];
    #pragma unroll
    for (int m = 0; m < 8; ++m) {
      long row0 = m0 + wr * 128 + m * 16 + (g << 2);
      #pragma unroll
      for (int i = 0; i < 4; ++i)
        out[(row0 + i) * (long)N + col] = acc[m][n][i] + bv;
    }
  }
}

extern "C" void kernel_launch(void* const* d_in, const int* in_sizes, int n_in,
                              void* d_out, int out_size, void* d_ws, size_t ws_size,
                              hipStream_t stream) {
  const float* x    = (const float*)d_in[0];
  const float* W    = (const float*)d_in[1];
  const float* b    = (const float*)d_in[2];
  const float* A    = (const float*)d_in[3];
  const float* Bm   = (const float*)d_in[4];

  const long D_out = in_sizes[2];                 // 4096
  const long D_in  = (long)in_sizes[1] / D_out;   // 4096
  const long M     = (long)in_sizes[0] / D_in;    // 16384
  const int  R     = (int)((long)in_sizes[3] / D_in);  // 16
  const int  K = (int)D_in, N = (int)D_out;

  unsigned short* xb = (unsigned short*)d_ws;
  unsigned short* wt = xb + (size_t)M * K;

  cvt_bf16_kernel<<<2048, 256, 0, stream>>>(x, xb, M * (long)K);
  build_wt_kernel<<<(K >> 6) * (N >> 6), 256, 0, stream>>>(W, A, Bm, wt, K, N, R);

  int grid = (int)((M / BM) * ((long)N / BN));    // 64 * 16 = 1024
  gemm_kernel<<<grid, 512, 128 * 1024, stream>>>(
      xb, wt, b, (float*)d_out, (int)M, N, K);
}